// Round 3
// baseline (6595.686 us; speedup 1.0000x reference)
//
#include <hip/hip_runtime.h>

#define TB 16
#define TSTEPS 256
#define INPUT 30
#define HID 128
#define HROW 132            // padded row stride for h buffers (floats)
#define XROW 32

__device__ __forceinline__ float sigf(float x) {
  return 1.0f / (1.0f + __expf(-x));
}
__device__ __forceinline__ float tanhfast(float x) {
  return 1.0f - 2.0f / (1.0f + __expf(2.0f * x));
}

__global__ __launch_bounds__(256, 1)
void lstm_fused(const float* __restrict__ x,
                const float* __restrict__ W_ih,
                const float* __restrict__ W_hh,
                const float* __restrict__ b_ih,
                const float* __restrict__ b_hh,
                const float* __restrict__ W0,
                const float* __restrict__ b0v,
                const float* __restrict__ W1,
                const float* __restrict__ b1v,
                float* __restrict__ out)
{
  __shared__ float hbuf[2][TB * HROW];
  __shared__ float xls[TB * XROW];
  __shared__ float clds[TB * HID];
  __shared__ float y0ls[TB * HROW];

  const int tid = threadIdx.x;
  const int wg = blockIdx.x;
  const int bbase = wg * TB;
  const int ug = tid >> 2;   // 0..63 : unit group
  const int kg = tid & 3;    // 0..3  : K-slice group

  // ---- load weight slices into registers ----
  // thread owns units u = ug + 64*j (j=0..7), K-slice [32*kg, 32*kg+32)
  float whh[8][32];
  float wih[8][8];
  float bias[8];
  #pragma unroll
  for (int j = 0; j < 8; ++j) {
    const int u = ug + 64 * j;
    const float4* row = reinterpret_cast<const float4*>(W_hh + u * HID + kg * 32);
    #pragma unroll
    for (int k4 = 0; k4 < 8; ++k4) {
      float4 v = row[k4];
      whh[j][k4*4+0] = v.x; whh[j][k4*4+1] = v.y;
      whh[j][k4*4+2] = v.z; whh[j][k4*4+3] = v.w;
    }
    #pragma unroll
    for (int i = 0; i < 8; ++i) {
      const int ii = kg * 8 + i;
      wih[j][i] = (ii < INPUT) ? W_ih[u * INPUT + ii] : 0.0f;
    }
    bias[j] = (kg == 0) ? (b_ih[u] + b_hh[u]) : 0.0f;
  }

  // ---- zero init ----
  for (int idx = tid; idx < TB * HROW; idx += 256) hbuf[0][idx] = 0.0f;
  for (int idx = tid; idx < TB * HID; idx += 256) clds[idx] = 0.0f;
  if (tid < TB) { xls[tid * XROW + 30] = 0.0f; xls[tid * XROW + 31] = 0.0f; }

  int p = 0;
  for (int t = 0; t < TSTEPS; ++t) {
    __syncthreads();
    // stage x[:, t, :] (16 samples x 30 floats)
    if (tid < 240) {
      const int s = tid / 15;
      const int i0 = (tid % 15) * 2;
      const float2 v = *reinterpret_cast<const float2*>(
          x + (size_t)(bbase + s) * (TSTEPS * INPUT) + t * INPUT + i0);
      xls[s * XROW + i0]     = v.x;
      xls[s * XROW + i0 + 1] = v.y;
    }
    __syncthreads();

    const float* hr = hbuf[p];
    float* hw = hbuf[p ^ 1];

    for (int s = 0; s < TB; ++s) {
      // h K-slice into registers (broadcast-friendly LDS reads)
      float hk[32];
      const float4* hr4 = reinterpret_cast<const float4*>(hr + s * HROW + kg * 32);
      #pragma unroll
      for (int k4 = 0; k4 < 8; ++k4) {
        float4 v = hr4[k4];
        hk[k4*4+0]=v.x; hk[k4*4+1]=v.y; hk[k4*4+2]=v.z; hk[k4*4+3]=v.w;
      }
      float xk[8];
      {
        const float4* xr4 = reinterpret_cast<const float4*>(xls + s * XROW + kg * 8);
        const float4 a = xr4[0], b = xr4[1];
        xk[0]=a.x; xk[1]=a.y; xk[2]=a.z; xk[3]=a.w;
        xk[4]=b.x; xk[5]=b.y; xk[6]=b.z; xk[7]=b.w;
      }
      float acc[8];
      #pragma unroll
      for (int j = 0; j < 8; ++j) acc[j] = bias[j];
      #pragma unroll
      for (int i = 0; i < 8; ++i)
        #pragma unroll
        for (int j = 0; j < 8; ++j)
          acc[j] = fmaf(wih[j][i], xk[i], acc[j]);
      #pragma unroll
      for (int k = 0; k < 32; ++k)
        #pragma unroll
        for (int j = 0; j < 8; ++j)
          acc[j] = fmaf(whh[j][k], hk[k], acc[j]);
      // reduce partial dots across the 4 kg lanes (adjacent lanes)
      #pragma unroll
      for (int j = 0; j < 8; ++j) {
        acc[j] += __shfl_xor(acc[j], 1, 64);
        acc[j] += __shfl_xor(acc[j], 2, 64);
      }
      // one of the 4 lanes owns this sample's gate update
      if (kg == (s & 3)) {
        const float ig0 = sigf(acc[0]),     ig1 = sigf(acc[1]);
        const float fg0 = sigf(acc[2]),     fg1 = sigf(acc[3]);
        const float gg0 = tanhfast(acc[4]), gg1 = tanhfast(acc[5]);
        const float og0 = sigf(acc[6]),     og1 = sigf(acc[7]);
        float c0 = clds[s * HID + ug];
        float c1 = clds[s * HID + ug + 64];
        c0 = fg0 * c0 + ig0 * gg0;
        c1 = fg1 * c1 + ig1 * gg1;
        clds[s * HID + ug]      = c0;
        clds[s * HID + ug + 64] = c1;
        hw[s * HROW + ug]       = og0 * tanhfast(c0);
        hw[s * HROW + ug + 64]  = og1 * tanhfast(c1);
      }
    }
    p ^= 1;
  }
  __syncthreads();

  // ---- head: y0 = relu(h @ W0^T + b0) ----
  const float* hf = hbuf[p];
  {
    const int s = tid >> 4;          // 0..15
    const int n0 = (tid & 15) * 8;   // 8 output units each
    float acc[8];
    #pragma unroll
    for (int nj = 0; nj < 8; ++nj) acc[nj] = b0v[n0 + nj];
    const float4* h4 = reinterpret_cast<const float4*>(hf + s * HROW);
    #pragma unroll 8
    for (int k4 = 0; k4 < 32; ++k4) {
      const float4 hv = h4[k4];
      #pragma unroll
      for (int nj = 0; nj < 8; ++nj) {
        const float4 w = *reinterpret_cast<const float4*>(W0 + (n0 + nj) * HID + k4 * 4);
        acc[nj] = fmaf(hv.x, w.x, fmaf(hv.y, w.y, fmaf(hv.z, w.z, fmaf(hv.w, w.w, acc[nj]))));
      }
    }
    #pragma unroll
    for (int nj = 0; nj < 8; ++nj)
      y0ls[s * HROW + n0 + nj] = fmaxf(acc[nj], 0.0f);
  }
  __syncthreads();

  // ---- out = y0 @ W1^T + b1 ----
  if (tid < TB * 11) {
    const int s = tid / 11;
    const int oo = tid % 11;
    float acc = b1v[oo];
    const float4* y4 = reinterpret_cast<const float4*>(y0ls + s * HROW);
    const float4* w4 = reinterpret_cast<const float4*>(W1 + oo * HID);
    #pragma unroll 8
    for (int k4 = 0; k4 < 32; ++k4) {
      const float4 yv = y4[k4];
      const float4 wv = w4[k4];
      acc = fmaf(yv.x, wv.x, fmaf(yv.y, wv.y, fmaf(yv.z, wv.z, fmaf(yv.w, wv.w, acc))));
    }
    out[(size_t)(bbase + s) * 11 + oo] = acc;
  }
}

extern "C" void kernel_launch(void* const* d_in, const int* in_sizes, int n_in,
                              void* d_out, int out_size, void* d_ws, size_t ws_size,
                              hipStream_t stream) {
  const float* x    = (const float*)d_in[0];
  const float* W_ih = (const float*)d_in[1];
  const float* W_hh = (const float*)d_in[2];
  const float* b_ih = (const float*)d_in[3];
  const float* b_hh = (const float*)d_in[4];
  const float* W0   = (const float*)d_in[5];
  const float* b0   = (const float*)d_in[6];
  const float* W1   = (const float*)d_in[7];
  const float* b1   = (const float*)d_in[8];
  float* out = (float*)d_out;
  lstm_fused<<<256, 256, 0, stream>>>(x, W_ih, W_hh, b_ih, b_hh, W0, b0, W1, b1, out);
}

// Round 4
// 535.452 us; speedup vs baseline: 12.3180x; 12.3180x over previous
//
#include <hip/hip_runtime.h>

#define TT 256
#define II 30
#define HH 128
#define TB 16
#define AROW 168   // f16 elems per A-row: 16B-aligned (336B), bank-friendly

typedef _Float16 half8 __attribute__((ext_vector_type(8)));
typedef _Float16 half2v __attribute__((ext_vector_type(2)));
typedef float f32x4 __attribute__((ext_vector_type(4)));

__device__ __forceinline__ float sigf(float x) {
  return 1.0f / (1.0f + __expf(-x));
}
__device__ __forceinline__ float tanhfast(float x) {
  return 1.0f - 2.0f / (1.0f + __expf(2.0f * x));
}

__global__ __launch_bounds__(256, 1)
void lstm_mfma(const float* __restrict__ x,
               const float* __restrict__ W_ih,
               const float* __restrict__ W_hh,
               const float* __restrict__ b_ih,
               const float* __restrict__ b_hh,
               const float* __restrict__ W0,
               const float* __restrict__ b0v,
               const float* __restrict__ W1,
               const float* __restrict__ b1v,
               float* __restrict__ out)
{
  __shared__ __align__(16) _Float16 Ab[2][TB * AROW];  // [h(128) | x(30) | pad(2..)]
  __shared__ float y0ls[TB * 132];

  const int tid = threadIdx.x;
  const int bbase = blockIdx.x * TB;
  const int wv = tid >> 6;      // wave 0..3
  const int lane = tid & 63;
  const int col = lane & 15;    // B-col / A-row / D-col index
  const int grp = lane >> 4;    // k-slot group

  // ---- B-fragments (weights) in registers: 8 tiles (gate*2+sub) x 5 K-steps ----
  // tile -> units n = gate*128 + wv*32 + sub*16 + col ; each lane holds 4 gates
  // of the SAME units -> gate math is lane-local.
  half8 bf[8][5];
  float bias[8];
  #pragma unroll
  for (int gate = 0; gate < 4; ++gate) {
    #pragma unroll
    for (int sub = 0; sub < 2; ++sub) {
      const int tl = gate * 2 + sub;
      const int n = gate * 128 + wv * 32 + sub * 16 + col;
      #pragma unroll
      for (int ks = 0; ks < 4; ++ks) {
        const float4 p = *reinterpret_cast<const float4*>(W_hh + n * HH + ks * 32 + grp * 8);
        const float4 q = *reinterpret_cast<const float4*>(W_hh + n * HH + ks * 32 + grp * 8 + 4);
        bf[tl][ks] = (half8){(_Float16)p.x, (_Float16)p.y, (_Float16)p.z, (_Float16)p.w,
                             (_Float16)q.x, (_Float16)q.y, (_Float16)q.z, (_Float16)q.w};
      }
      {  // K-step 4: x-block, W_ih cols grp*8+j (valid < 30)
        float v[8];
        #pragma unroll
        for (int j = 0; j < 8; ++j) {
          const int cc = grp * 8 + j;
          v[j] = (cc < II) ? W_ih[n * II + cc] : 0.0f;
        }
        bf[tl][4] = (half8){(_Float16)v[0], (_Float16)v[1], (_Float16)v[2], (_Float16)v[3],
                            (_Float16)v[4], (_Float16)v[5], (_Float16)v[6], (_Float16)v[7]};
      }
      bias[tl] = b_ih[n] + b_hh[n];
    }
  }

  // ---- init LDS: h-part of buf0 = 0; pad cols 158/159 of both bufs = 0 ----
  {
    const int s = tid >> 4, u8 = (tid & 15) * 8;
    *reinterpret_cast<half8*>(&Ab[0][s * AROW + u8]) =
        (half8){0, 0, 0, 0, 0, 0, 0, 0};
  }
  if (tid < 32) {
    const int b = tid >> 4, s = tid & 15;
    *reinterpret_cast<half2v*>(&Ab[b][s * AROW + 158]) = (half2v){0, 0};
  }

  // ---- x staging lanes: 240 lanes x float2 per step ----
  const int sid_r = tid / 15;
  const int sid = sid_r < 15 ? sid_r : 15;
  const int i0 = (tid % 15) * 2;
  const bool stager = (tid < 240);
  const float* xp = x + (size_t)(bbase + sid) * (TT * II) + i0;
  if (stager) {
    const float2 v = *reinterpret_cast<const float2*>(xp);  // t = 0
    *reinterpret_cast<half2v*>(&Ab[0][sid * AROW + HH + i0]) =
        (half2v){(_Float16)v.x, (_Float16)v.y};
  }

  float c[2][4];
  #pragma unroll
  for (int s2 = 0; s2 < 2; ++s2)
    #pragma unroll
    for (int r = 0; r < 4; ++r) c[s2][r] = 0.0f;

  __syncthreads();

  // ================= recurrence =================
  for (int t = 0; t < TT; ++t) {
    const bool pre = stager && (t + 1 < TT);
    float2 xv = {0.0f, 0.0f};
    if (pre) xv = *reinterpret_cast<const float2*>(xp + (t + 1) * II);  // issue early

    const _Float16* Ar = Ab[t & 1];
    _Float16* Aw = Ab[(t + 1) & 1];

    half8 af[5];
    #pragma unroll
    for (int ks = 0; ks < 5; ++ks)
      af[ks] = *reinterpret_cast<const half8*>(&Ar[col * AROW + ks * 32 + grp * 8]);

    f32x4 acc[4][2];
    #pragma unroll
    for (int g = 0; g < 4; ++g)
      #pragma unroll
      for (int s2 = 0; s2 < 2; ++s2) {
        const float b = bias[g * 2 + s2];
        acc[g][s2] = (f32x4){b, b, b, b};
      }

    #pragma unroll
    for (int ks = 0; ks < 5; ++ks)
      #pragma unroll
      for (int g = 0; g < 4; ++g)
        #pragma unroll
        for (int s2 = 0; s2 < 2; ++s2)
          acc[g][s2] = __builtin_amdgcn_mfma_f32_16x16x32_f16(
              af[ks], bf[g * 2 + s2][ks], acc[g][s2], 0, 0, 0);

    // gates: lane-local i,f,g,o for 8 (sample,unit) pairs
    #pragma unroll
    for (int s2 = 0; s2 < 2; ++s2)
      #pragma unroll
      for (int r = 0; r < 4; ++r) {
        const float ig = sigf(acc[0][s2][r]);
        const float fg = sigf(acc[1][s2][r]);
        const float gg = tanhfast(acc[2][s2][r]);
        const float og = sigf(acc[3][s2][r]);
        const float cn = fg * c[s2][r] + ig * gg;
        c[s2][r] = cn;
        const float h = og * tanhfast(cn);
        Aw[(grp * 4 + r) * AROW + wv * 32 + s2 * 16 + col] = (_Float16)h;
      }

    if (pre)
      *reinterpret_cast<half2v*>(&Aw[sid * AROW + HH + i0]) =
          (half2v){(_Float16)xv.x, (_Float16)xv.y};

    __syncthreads();
  }

  // ================= head =================
  // final h (f16) is in Ab[0][s][0..127]
  {
    const int s = tid >> 4;
    const int n0 = (tid & 15) * 8;
    float acch[8];
    #pragma unroll
    for (int nj = 0; nj < 8; ++nj) acch[nj] = b0v[n0 + nj];
    #pragma unroll
    for (int kb = 0; kb < 16; ++kb) {
      const half8 hh = *reinterpret_cast<const half8*>(&Ab[0][s * AROW + kb * 8]);
      float hf[8];
      #pragma unroll
      for (int j = 0; j < 8; ++j) hf[j] = (float)hh[j];
      #pragma unroll
      for (int nj = 0; nj < 8; ++nj) {
        const float4 w0 = *reinterpret_cast<const float4*>(W0 + (n0 + nj) * HH + kb * 8);
        const float4 w1 = *reinterpret_cast<const float4*>(W0 + (n0 + nj) * HH + kb * 8 + 4);
        acch[nj] = fmaf(hf[0], w0.x, fmaf(hf[1], w0.y, fmaf(hf[2], w0.z, fmaf(hf[3], w0.w,
                   fmaf(hf[4], w1.x, fmaf(hf[5], w1.y, fmaf(hf[6], w1.z, fmaf(hf[7], w1.w,
                        acch[nj]))))))));
      }
    }
    #pragma unroll
    for (int nj = 0; nj < 8; ++nj)
      y0ls[s * 132 + n0 + nj] = fmaxf(acch[nj], 0.0f);
  }
  __syncthreads();

  if (tid < TB * 11) {
    const int s = tid / 11;
    const int oo = tid % 11;
    float acc1 = b1v[oo];
    const float4* y4 = reinterpret_cast<const float4*>(y0ls + s * 132);
    const float4* w4 = reinterpret_cast<const float4*>(W1 + oo * HH);
    #pragma unroll 8
    for (int k4 = 0; k4 < 32; ++k4) {
      const float4 yv = y4[k4];
      const float4 wv4 = w4[k4];
      acc1 = fmaf(yv.x, wv4.x, fmaf(yv.y, wv4.y, fmaf(yv.z, wv4.z, fmaf(yv.w, wv4.w, acc1))));
    }
    out[(size_t)(bbase + s) * 11 + oo] = acc1;
  }
}

extern "C" void kernel_launch(void* const* d_in, const int* in_sizes, int n_in,
                              void* d_out, int out_size, void* d_ws, size_t ws_size,
                              hipStream_t stream) {
  const float* x    = (const float*)d_in[0];
  const float* W_ih = (const float*)d_in[1];
  const float* W_hh = (const float*)d_in[2];
  const float* b_ih = (const float*)d_in[3];
  const float* b_hh = (const float*)d_in[4];
  const float* W0   = (const float*)d_in[5];
  const float* b0   = (const float*)d_in[6];
  const float* W1   = (const float*)d_in[7];
  const float* b1   = (const float*)d_in[8];
  float* out = (float*)d_out;
  lstm_mfma<<<256, 256, 0, stream>>>(x, W_ih, W_hh, b_ih, b_hh, W0, b0, W1, b1, out);
}

// Round 5
// 276.767 us; speedup vs baseline: 23.8312x; 1.9347x over previous
//
#include <hip/hip_runtime.h>

#define TT 256
#define II 30
#define HH 128
#define TB 16
#define AROW 168   // f16 elems per A-row (16B-aligned: 336B)

typedef _Float16 half8 __attribute__((ext_vector_type(8)));
typedef float f32x4 __attribute__((ext_vector_type(4)));

// v_rcp_f32-based fast gates (<=1 ulp rcp; negligible vs f16 panel quantization)
__device__ __forceinline__ float sigf(float x) {
  return __builtin_amdgcn_rcpf(1.0f + __expf(-x));
}
__device__ __forceinline__ float tanhfast(float x) {
  return fmaf(-2.0f, __builtin_amdgcn_rcpf(1.0f + __expf(2.0f * x)), 1.0f);
}

__global__ __launch_bounds__(512, 2)
void lstm_mfma(const float* __restrict__ x,
               const float* __restrict__ W_ih,
               const float* __restrict__ W_hh,
               const float* __restrict__ b_ih,
               const float* __restrict__ b_hh,
               const float* __restrict__ W0,
               const float* __restrict__ b0v,
               const float* __restrict__ W1,
               const float* __restrict__ b1v,
               float* __restrict__ out)
{
  __shared__ __align__(16) _Float16 Ab[2][TB * AROW];  // [h(128) | x(30) | pad]
  __shared__ float y0ls[TB * 132];

  const int tid = threadIdx.x;
  const int bbase = blockIdx.x * TB;
  const int w = tid >> 6;       // wave 0..7
  const int lane = tid & 63;
  const int col = lane & 15;    // MFMA col (unit within tile) / A-row (sample)
  const int grp = lane >> 4;    // k-slot group

  // ---- B-fragments: wave w owns units [w*16, w*16+16) for all 4 gates ----
  // lane holds i,f,g,o of the SAME unit -> gate math fully lane-local.
  half8 bf[4][5];
  float bias[4];
  #pragma unroll
  for (int g = 0; g < 4; ++g) {
    const int n = g * 128 + w * 16 + col;
    #pragma unroll
    for (int ks = 0; ks < 4; ++ks) {
      const float4 p = *reinterpret_cast<const float4*>(W_hh + n * HH + ks * 32 + grp * 8);
      const float4 q = *reinterpret_cast<const float4*>(W_hh + n * HH + ks * 32 + grp * 8 + 4);
      bf[g][ks] = (half8){(_Float16)p.x, (_Float16)p.y, (_Float16)p.z, (_Float16)p.w,
                          (_Float16)q.x, (_Float16)q.y, (_Float16)q.z, (_Float16)q.w};
    }
    {  // K-step 4: x block (W_ih cols grp*8+j, valid < 30)
      float v[8];
      #pragma unroll
      for (int j = 0; j < 8; ++j) {
        const int cc = grp * 8 + j;
        v[j] = (cc < II) ? W_ih[n * II + cc] : 0.0f;
      }
      bf[g][4] = (half8){(_Float16)v[0], (_Float16)v[1], (_Float16)v[2], (_Float16)v[3],
                         (_Float16)v[4], (_Float16)v[5], (_Float16)v[6], (_Float16)v[7]};
    }
    bias[g] = b_ih[n] + b_hh[n];
  }

  // ---- x staging: 60 lanes/wave, 2 samples/wave, 1 float each ----
  const bool stg = (lane < 60);
  const int sS = w * 2 + (lane >= 30 ? 1 : 0);
  const int iS = lane % 30;
  const float* xp = x + (size_t)(bbase + sS) * (TT * II) + iS;
  float xa = 0.0f, xb = 0.0f;
  if (stg) { xa = xp[0]; xb = xp[II]; }   // t=0 and t=1

  // ---- init LDS ----
  if (tid < 256) {
    const int s = tid >> 4, u8 = (tid & 15) * 8;
    *reinterpret_cast<half8*>(&Ab[0][s * AROW + u8]) = (half8){0,0,0,0,0,0,0,0};
  }
  if (tid < 32) {  // zero pad cols 158,159 of both buffers (k=158,159 pair with zero B)
    const int b = tid >> 4, s = tid & 15;
    Ab[b][s * AROW + 158] = (_Float16)0.0f;
    Ab[b][s * AROW + 159] = (_Float16)0.0f;
  }
  if (stg) Ab[0][sS * AROW + HH + iS] = (_Float16)xa;

  float c[4] = {0.0f, 0.0f, 0.0f, 0.0f};
  __syncthreads();

  // ================= recurrence =================
  for (int t = 0; t < TT; ++t) {
    float xn = 0.0f;
    const bool p2 = stg && (t + 2 < TT);
    if (p2) xn = xp[(size_t)(t + 2) * II];   // 2-step-deep prefetch

    const _Float16* Ar = Ab[t & 1];
    _Float16* Aw = Ab[(t + 1) & 1];

    half8 af[5];
    #pragma unroll
    for (int ks = 0; ks < 5; ++ks)
      af[ks] = *reinterpret_cast<const half8*>(&Ar[col * AROW + ks * 32 + grp * 8]);

    f32x4 acc[4];
    #pragma unroll
    for (int g = 0; g < 4; ++g) {
      const float b = bias[g];
      acc[g] = (f32x4){b, b, b, b};
    }
    #pragma unroll
    for (int ks = 0; ks < 5; ++ks)
      #pragma unroll
      for (int g = 0; g < 4; ++g)
        acc[g] = __builtin_amdgcn_mfma_f32_16x16x32_f16(af[ks], bf[g][ks], acc[g], 0, 0, 0);

    // gates: lane-local i,f,g,o for 4 (sample,unit) pairs
    #pragma unroll
    for (int r = 0; r < 4; ++r) {
      const float ig = sigf(acc[0][r]);
      const float fg = sigf(acc[1][r]);
      const float gg = tanhfast(acc[2][r]);
      const float og = sigf(acc[3][r]);
      const float cn = fmaf(fg, c[r], ig * gg);
      c[r] = cn;
      const float h = og * tanhfast(cn);
      Aw[(grp * 4 + r) * AROW + w * 16 + col] = (_Float16)h;
    }

    if (stg && (t + 1 < TT)) Aw[sS * AROW + HH + iS] = (_Float16)xb;
    __syncthreads();
    xb = xn;
  }

  // ================= head =================
  // final h (f16) is in Ab[0][s][0..127]
  if (tid < 256) {
    const int s = tid >> 4;
    const int n0 = (tid & 15) * 8;
    float acch[8];
    #pragma unroll
    for (int nj = 0; nj < 8; ++nj) acch[nj] = b0v[n0 + nj];
    #pragma unroll
    for (int kb = 0; kb < 16; ++kb) {
      const half8 hh = *reinterpret_cast<const half8*>(&Ab[0][s * AROW + kb * 8]);
      float hf[8];
      #pragma unroll
      for (int j = 0; j < 8; ++j) hf[j] = (float)hh[j];
      #pragma unroll
      for (int nj = 0; nj < 8; ++nj) {
        const float4 w0 = *reinterpret_cast<const float4*>(W0 + (n0 + nj) * HH + kb * 8);
        const float4 w1 = *reinterpret_cast<const float4*>(W0 + (n0 + nj) * HH + kb * 8 + 4);
        acch[nj] = fmaf(hf[0], w0.x, fmaf(hf[1], w0.y, fmaf(hf[2], w0.z, fmaf(hf[3], w0.w,
                   fmaf(hf[4], w1.x, fmaf(hf[5], w1.y, fmaf(hf[6], w1.z, fmaf(hf[7], w1.w,
                        acch[nj]))))))));
      }
    }
    #pragma unroll
    for (int nj = 0; nj < 8; ++nj)
      y0ls[s * 132 + n0 + nj] = fmaxf(acch[nj], 0.0f);
  }
  __syncthreads();

  if (tid < TB * 11) {
    const int s = tid / 11;
    const int oo = tid % 11;
    float acc1 = b1v[oo];
    const float4* y4 = reinterpret_cast<const float4*>(y0ls + s * 132);
    const float4* w4 = reinterpret_cast<const float4*>(W1 + oo * HH);
    #pragma unroll 8
    for (int k4 = 0; k4 < 32; ++k4) {
      const float4 yv = y4[k4];
      const float4 wv4 = w4[k4];
      acc1 = fmaf(yv.x, wv4.x, fmaf(yv.y, wv4.y, fmaf(yv.z, wv4.z, fmaf(yv.w, wv4.w, acc1))));
    }
    out[(size_t)(bbase + s) * 11 + oo] = acc1;
  }
}

extern "C" void kernel_launch(void* const* d_in, const int* in_sizes, int n_in,
                              void* d_out, int out_size, void* d_ws, size_t ws_size,
                              hipStream_t stream) {
  const float* x    = (const float*)d_in[0];
  const float* W_ih = (const float*)d_in[1];
  const float* W_hh = (const float*)d_in[2];
  const float* b_ih = (const float*)d_in[3];
  const float* b_hh = (const float*)d_in[4];
  const float* W0   = (const float*)d_in[5];
  const float* b0   = (const float*)d_in[6];
  const float* W1   = (const float*)d_in[7];
  const float* b1   = (const float*)d_in[8];
  float* out = (float*)d_out;
  lstm_mfma<<<256, 512, 0, stream>>>(x, W_ih, W_hh, b_ih, b_hh, W0, b0, W1, b1, out);
}